// Round 1
// baseline (663.219 us; speedup 1.0000x reference)
//
#include <hip/hip_runtime.h>

// MultiLIF forward: B=32, L=2048, K=1024, f32.
// One thread per (b,k) neuron, sequential loop over t.
// Exact-IEEE mirror of the numpy/jax op order (no FMA contraction, real
// correctly-rounded f32 division) so hard-spike decisions match bitwise.

#define BATCH 32
#define SEQL  2048
#define KDIM  1024
#define PLANE (BATCH * SEQL * KDIM)  // 67108864 elements per output

__global__ __launch_bounds__(64) void multilif_fwd(const float* __restrict__ I,
                                                   float* __restrict__ out) {
#pragma clang fp contract(off)
    const int idx = blockIdx.x * 64 + threadIdx.x;      // 0 .. 32767
    const int b = idx >> 10;                            // / KDIM
    const int k = idx & (KDIM - 1);

    const size_t base = ((size_t)b * SEQL) * KDIM + k;
    const float* __restrict__ Ip = I + base;
    float* __restrict__ sp = out + base;                 // spikes
    float* __restrict__ se = out + (size_t)PLANE + base; // series (running sum)
    float* __restrict__ vq = out + 2 * (size_t)PLANE + base; // v_seq (pre-reset)

    float v = 0.0f;
    float a = 0.0f;
    float sn = 0.0f;

#pragma unroll 4
    for (int t = 0; t < SEQL; ++t) {
        const size_t off = (size_t)t * KDIM;
        const float It = Ip[off];

        // th_eff = TH + BETA_ADAPT * a   (separate mul, then add — no FMA)
        const float th = 1.5f + 1.5f * a;

        // v = v + (-v/TAU + I_t)   (correctly-rounded division, separate adds)
        v = v + (-v / 20.0f + It);

        const float s = (v >= th) ? 1.0f : 0.0f;
        sn = sn + s;

        sp[off] = s;
        se[off] = sn;
        vq[off] = v;   // pre-reset membrane potential

        // v_next = v*(1-s) + V_RESET*s  ==  (s ? -0.5 : v)  exactly, s in {0,1}
        v = (v >= th) ? -0.5f : v;

        // a_next = a + (-a/TAU_ADAPT + s)
        a = a + (-a / 100.0f + s);
    }
}

extern "C" void kernel_launch(void* const* d_in, const int* in_sizes, int n_in,
                              void* d_out, int out_size, void* d_ws, size_t ws_size,
                              hipStream_t stream) {
    const float* I = (const float*)d_in[0];
    float* out = (float*)d_out;

    const int total = BATCH * KDIM;          // 32768 independent neurons
    const int block = 64;
    const int grid = total / block;          // 512 blocks -> 2 waves / CU

    multilif_fwd<<<grid, block, 0, stream>>>(I, out);
}

// Round 2
// 253.458 us; speedup vs baseline: 2.6167x; 2.6167x over previous
//
#include <hip/hip_runtime.h>

// MultiLIF forward: B=32, L=2048, K=1024, f32.
// One thread per (b,k) neuron, sequential over t. Only 512 waves exist
// (B*K/64), so ~1 wave/SIMD: ALL latency hiding must come from ILP.
// => explicit 16-deep prefetch ring for I (loads are recurrence-independent),
//    nontemporal stores for the 3 write-only output streams.
// Exact-IEEE mirror of the reference op order (no FMA contraction, real
// correctly-rounded f32 division) so hard-spike decisions match.

#define BATCH 32
#define SEQL  2048
#define KDIM  1024
#define PLANE (BATCH * SEQL * KDIM)  // 67108864 elements per output plane

__global__ __launch_bounds__(64, 1) void multilif_fwd(const float* __restrict__ I,
                                                      float* __restrict__ out) {
#pragma clang fp contract(off)
    const int idx = blockIdx.x * 64 + threadIdx.x;      // 0 .. 32767
    const size_t base = ((size_t)(idx >> 10) * SEQL) * KDIM + (idx & (KDIM - 1));

    const float* __restrict__ Ip = I + base;
    float* __restrict__ sp = out + base;                      // spikes
    float* __restrict__ se = out + (size_t)PLANE + base;      // series (running sum)
    float* __restrict__ vq = out + 2 * (size_t)PLANE + base;  // v_seq (pre-reset)

    float v = 0.0f;
    float a = 0.0f;
    float sn = 0.0f;

    constexpr int PF = 16;               // prefetch depth (loads in flight)
    float buf[PF];                       // statically-indexed ring (full unroll)

#pragma unroll
    for (int j = 0; j < PF; ++j)
        buf[j] = Ip[(size_t)j * KDIM];

    // one simulation step; v/a/sn updated in registers, 3 streaming stores
#define STEP(IT, OFF)                                            \
    do {                                                         \
        const float th = 1.5f + 1.5f * a;   /* no FMA */         \
        v = v + (-v / 20.0f + (IT));        /* IEEE divide */    \
        const float s = (v >= th) ? 1.0f : 0.0f;                 \
        sn = sn + s;                                             \
        __builtin_nontemporal_store(s,  sp + (OFF));             \
        __builtin_nontemporal_store(sn, se + (OFF));             \
        __builtin_nontemporal_store(v,  vq + (OFF));             \
        v = (v >= th) ? -0.5f : v;          /* exact reset  */   \
        a = a + (-a / 100.0f + s);                               \
    } while (0)

    // main: 127 chunks of PF steps, always prefetching PF ahead
    for (int tb = 0; tb < SEQL - PF; tb += PF) {
#pragma unroll
        for (int j = 0; j < PF; ++j) {
            const size_t off = (size_t)(tb + j) * KDIM;
            const float It = buf[j];
            buf[j] = Ip[off + (size_t)PF * KDIM];   // prefetch t+PF
            STEP(It, off);
        }
    }
    // tail: last PF steps, no prefetch
    {
        const int tb = SEQL - PF;
#pragma unroll
        for (int j = 0; j < PF; ++j) {
            const size_t off = (size_t)(tb + j) * KDIM;
            STEP(buf[j], off);
        }
    }
#undef STEP
}

extern "C" void kernel_launch(void* const* d_in, const int* in_sizes, int n_in,
                              void* d_out, int out_size, void* d_ws, size_t ws_size,
                              hipStream_t stream) {
    const float* I = (const float*)d_in[0];
    float* out = (float*)d_out;

    const int total = BATCH * KDIM;          // 32768 independent neurons
    const int block = 64;
    const int grid = total / block;          // 512 blocks -> 2 waves / CU

    multilif_fwd<<<grid, block, 0, stream>>>(I, out);
}

// Round 3
// 218.803 us; speedup vs baseline: 3.0311x; 1.1584x over previous
//
#include <hip/hip_runtime.h>

// MultiLIF forward: B=32, L=2048, K=1024, f32.
// Producer-consumer wave specialization: only 512 compute waves exist
// (one thread per neuron), so stores are offloaded to 3 dedicated store
// waves per block -> 8 waves/CU issuing memory instead of 2.
//   block = 256 threads: wave0 = compute (64 neurons), waves 1-3 = one
//   output plane each. 16-step chunks, double-buffered LDS, raw
//   lgkmcnt-only barrier so nt-stores pipeline across chunks.
// Arithmetic bit-identical to the verified round-1 kernel (no FMA
// contraction, IEEE divides, exact 0/1 spike select).

#define BATCH 32
#define SEQL  2048
#define KDIM  1024
#define PLANE (BATCH * SEQL * KDIM)   // 67108864 elements per output plane
#define CHUNK 16
#define NCHUNK (SEQL / CHUNK)         // 128

__device__ __forceinline__ void sync_lds() {
    // order LDS ops only; leave global (nt) stores in flight across barrier
    asm volatile("s_waitcnt lgkmcnt(0)" ::: "memory");
    __builtin_amdgcn_s_barrier();
}

__global__ __launch_bounds__(256, 2) void multilif_fwd(const float* __restrict__ I,
                                                       float* __restrict__ out) {
    __shared__ float lds[2][CHUNK][3][64];   // [buf][step][plane][lane] = 24 KB

    const int wid  = threadIdx.x >> 6;
    const int lane = threadIdx.x & 63;
    const int idx  = blockIdx.x * 64 + lane;             // neuron id
    const size_t base = ((size_t)(idx >> 10) * SEQL) * KDIM + (idx & (KDIM - 1));

    if (wid == 0) {
        // ------------- compute wave -------------
        const float* __restrict__ Ip = I + base;
        float v = 0.0f, a = 0.0f, sn = 0.0f;
        float ringA[CHUNK], ringB[CHUNK];

#pragma unroll
        for (int j = 0; j < CHUNK; ++j) ringA[j] = Ip[(size_t)j * KDIM];

        auto compute_chunk = [&](int c, float (&cur)[CHUNK], float (&nxt)[CHUNK],
                                 bool pre) {
#pragma clang fp contract(off)
            // issue next chunk's loads first (stay in flight during compute)
#pragma unroll
            for (int j = 0; j < CHUNK; ++j)
                if (pre) nxt[j] = Ip[(size_t)((c + 1) * CHUNK + j) * KDIM];
            const int bs = c & 1;
#pragma unroll
            for (int j = 0; j < CHUNK; ++j) {
                const float It = cur[j];
                const float th = 1.5f + 1.5f * a;      // no FMA
                v = v + (-v / 20.0f + It);             // IEEE divide
                const float s = (v >= th) ? 1.0f : 0.0f;
                sn = sn + s;
                lds[bs][j][0][lane] = s;
                lds[bs][j][1][lane] = sn;
                lds[bs][j][2][lane] = v;               // pre-reset v
                v = (v >= th) ? -0.5f : v;             // exact reset
                a = a + (-a / 100.0f + s);
            }
        };

        for (int cc = 0; cc < NCHUNK / 2; ++cc) {
            compute_chunk(2 * cc,     ringA, ringB, true);
            sync_lds();
            compute_chunk(2 * cc + 1, ringB, ringA, cc < NCHUNK / 2 - 1);
            sync_lds();
        }
    } else {
        // ------------- store waves: one output plane each -------------
        const int p = wid - 1;
        float* __restrict__ pb = out + (size_t)p * (size_t)PLANE + base;

        for (int c = 0; c < NCHUNK; ++c) {
            sync_lds();                       // chunk c now ready in lds[c&1]
            const int bs = c & 1;
            float r[CHUNK];
#pragma unroll
            for (int j = 0; j < CHUNK; ++j) r[j] = lds[bs][j][p][lane];
#pragma unroll
            for (int j = 0; j < CHUNK; ++j)
                __builtin_nontemporal_store(r[j], pb + (size_t)(c * CHUNK + j) * KDIM);
        }
    }
}

extern "C" void kernel_launch(void* const* d_in, const int* in_sizes, int n_in,
                              void* d_out, int out_size, void* d_ws, size_t ws_size,
                              hipStream_t stream) {
    const float* I = (const float*)d_in[0];
    float* out = (float*)d_out;

    const int grid = (BATCH * KDIM) / 64;    // 512 blocks (64 neurons each)
    multilif_fwd<<<grid, 256, 0, stream>>>(I, out);
}

// Round 4
// 213.083 us; speedup vs baseline: 3.1125x; 1.0268x over previous
//
#include <hip/hip_runtime.h>

// MultiLIF forward: B=32, L=2048, K=1024, f32.
// Producer-consumer wave specialization: wave0 computes the serial
// recurrence for 64 neurons; waves 1-3 drain one output plane each from
// LDS to global with nontemporal stores (8 mem-issuing waves/CU).
// Round 3 change: CHUNK 16 -> 32. Halves barrier count (64 total),
// doubles store burst depth and the I-prefetch lead (~2000 cyc).
// Arithmetic bit-identical to the verified round-1 kernel (no FMA
// contraction, IEEE divides, exact 0/1 spike select).

#define BATCH 32
#define SEQL  2048
#define KDIM  1024
#define PLANE (BATCH * SEQL * KDIM)   // 67108864 elements per output plane
#define CHUNK 32
#define NCHUNK (SEQL / CHUNK)         // 64

__device__ __forceinline__ void sync_lds() {
    // order LDS ops only; leave global (nt) stores in flight across barrier
    asm volatile("s_waitcnt lgkmcnt(0)" ::: "memory");
    __builtin_amdgcn_s_barrier();
}

__global__ __launch_bounds__(256, 2) void multilif_fwd(const float* __restrict__ I,
                                                       float* __restrict__ out) {
    __shared__ float lds[2][CHUNK][3][64];   // [buf][step][plane][lane] = 48 KB

    const int wid  = threadIdx.x >> 6;
    const int lane = threadIdx.x & 63;
    const int idx  = blockIdx.x * 64 + lane;             // neuron id
    const size_t base = ((size_t)(idx >> 10) * SEQL) * KDIM + (idx & (KDIM - 1));

    if (wid == 0) {
        // ------------- compute wave -------------
        const float* __restrict__ Ip = I + base;
        float v = 0.0f, a = 0.0f, sn = 0.0f;
        float ringA[CHUNK], ringB[CHUNK];

#pragma unroll
        for (int j = 0; j < CHUNK; ++j) ringA[j] = Ip[(size_t)j * KDIM];

        auto compute_chunk = [&](int c, float (&cur)[CHUNK], float (&nxt)[CHUNK],
                                 bool pre) {
#pragma clang fp contract(off)
            // issue next chunk's loads first (stay in flight during compute)
#pragma unroll
            for (int j = 0; j < CHUNK; ++j)
                if (pre) nxt[j] = Ip[(size_t)((c + 1) * CHUNK + j) * KDIM];
            const int bs = c & 1;
#pragma unroll
            for (int j = 0; j < CHUNK; ++j) {
                const float It = cur[j];
                const float th = 1.5f + 1.5f * a;      // no FMA
                v = v + (-v / 20.0f + It);             // IEEE divide
                const float s = (v >= th) ? 1.0f : 0.0f;
                sn = sn + s;
                lds[bs][j][0][lane] = s;
                lds[bs][j][1][lane] = sn;
                lds[bs][j][2][lane] = v;               // pre-reset v
                v = (v >= th) ? -0.5f : v;             // exact reset
                a = a + (-a / 100.0f + s);
            }
        };

        for (int cc = 0; cc < NCHUNK / 2; ++cc) {
            compute_chunk(2 * cc,     ringA, ringB, true);
            sync_lds();
            compute_chunk(2 * cc + 1, ringB, ringA, cc < NCHUNK / 2 - 1);
            sync_lds();
        }
    } else {
        // ------------- store waves: one output plane each -------------
        const int p = wid - 1;
        float* __restrict__ pb = out + (size_t)p * (size_t)PLANE + base;

        for (int c = 0; c < NCHUNK; ++c) {
            sync_lds();                       // chunk c now ready in lds[c&1]
            const int bs = c & 1;
            float r[CHUNK];
#pragma unroll
            for (int j = 0; j < CHUNK; ++j) r[j] = lds[bs][j][p][lane];
#pragma unroll
            for (int j = 0; j < CHUNK; ++j)
                __builtin_nontemporal_store(r[j], pb + (size_t)(c * CHUNK + j) * KDIM);
        }
    }
}

extern "C" void kernel_launch(void* const* d_in, const int* in_sizes, int n_in,
                              void* d_out, int out_size, void* d_ws, size_t ws_size,
                              hipStream_t stream) {
    const float* I = (const float*)d_in[0];
    float* out = (float*)d_out;

    const int grid = (BATCH * KDIM) / 64;    // 512 blocks (64 neurons each)
    multilif_fwd<<<grid, 256, 0, stream>>>(I, out);
}